// Round 1
// baseline (3357.210 us; speedup 1.0000x reference)
//
#include <hip/hip_runtime.h>
#include <math.h>

// M3GNet-like GNN forward. N=10000 nodes, E=160000 edges, T=1200000 triplets,
// D=256, DM=64, H=1024, L=3, output = scalar mean energy (fp32).
//
// Strategy (R0): fp32 vector-ALU everywhere (no fp32 MFMA on CDNA4).
// - CSR segmentation of triplets by t_dst (hist+scan+scatter, every call).
// - Wave-per-edge online-softmax triplet kernel (lane = channel).
// - Fused RBF+GEMM for xij (y never materialized).
// - FFN as two LDS-tiled fp32 GEMMs.

#define DM 64
#define DMODEL 256
#define HDIM 1024

__global__ void k_embed(const int* __restrict__ an, const float* __restrict__ emb,
                        float* __restrict__ x) {
    int n = blockIdx.x;
    int d = threadIdx.x;          // blockDim = 256
    x[n * DMODEL + d] = emb[an[n] * DMODEL + d];
}

__global__ void k_edge_geom(const float* __restrict__ r, float* __restrict__ bl,
                            float* __restrict__ rn, int E) {
    int e = blockIdx.x * blockDim.x + threadIdx.x;
    if (e >= E) return;
    float a = r[e * 3 + 0], b = r[e * 3 + 1], c = r[e * 3 + 2];
    float l = sqrtf(a * a + b * b + c * c);
    bl[e] = l;
    float inv = 1.0f / l;
    // note: reference uses -r/|r| for both operands of the dot; signs cancel.
    rn[e * 3 + 0] = a * inv;
    rn[e * 3 + 1] = b * inv;
    rn[e * 3 + 2] = c * inv;
}

__global__ void k_hist(const int* __restrict__ td, int* __restrict__ cnt, int T) {
    int t = blockIdx.x * blockDim.x + threadIdx.x;
    if (t < T) atomicAdd(&cnt[td[t]], 1);
}

// single-block exclusive scan over cnt[E] -> rowp[E+1]
__global__ void k_scan(const int* __restrict__ cnt, int* __restrict__ rowp,
                       int E, int T) {
    __shared__ int sm[1024];
    int tid = threadIdx.x;
    int chunk = (E + 1023) >> 10;
    int lo = tid * chunk;
    int hi = min(E, lo + chunk);
    int s = 0;
    for (int i = lo; i < hi; ++i) s += cnt[i];
    sm[tid] = s;
    __syncthreads();
    for (int off = 1; off < 1024; off <<= 1) {
        int v = (tid >= off) ? sm[tid - off] : 0;
        __syncthreads();
        sm[tid] += v;
        __syncthreads();
    }
    int run = (tid == 0) ? 0 : sm[tid - 1];
    for (int i = lo; i < hi; ++i) { rowp[i] = run; run += cnt[i]; }
    if (tid == 0) rowp[E] = T;
}

// scatter triplets into segment order; fuse theta computation; permute t_src.
__global__ void k_scatter(const int* __restrict__ ts, const int* __restrict__ td,
                          const int* __restrict__ rowp, int* __restrict__ cursor,
                          const float* __restrict__ rn,
                          int* __restrict__ srcs, float* __restrict__ thetas, int T) {
    int t = blockIdx.x * blockDim.x + threadIdx.x;
    if (t >= T) return;
    int a = ts[t], b = td[t];
    float d = rn[a * 3 + 0] * rn[b * 3 + 0]
            + rn[a * 3 + 1] * rn[b * 3 + 1]
            + rn[a * 3 + 2] * rn[b * 3 + 2];
    d = fminf(1.0f, fmaxf(-1.0f, d));
    float th = acosf(d);
    int pos = rowp[b] + atomicAdd(&cursor[b], 1);
    srcs[pos] = a;
    thetas[pos] = th;
}

// xs = x@Wsrc + bsrc ; xd = x@Wdst + bdst   (wave per node, lane = dm)
__global__ __launch_bounds__(256) void k_node_proj(
    const float* __restrict__ x,
    const float* __restrict__ Ws, const float* __restrict__ bs,
    const float* __restrict__ Wd, const float* __restrict__ bd,
    float* __restrict__ xs, float* __restrict__ xd, int N) {
    int lane = threadIdx.x & 63;
    int n = blockIdx.x * 4 + (threadIdx.x >> 6);
    if (n >= N) return;
    const float* xr = x + (size_t)n * DMODEL;
    float as = 0.f, ad = 0.f;
    for (int d = 0; d < DMODEL; ++d) {
        float xv = xr[d];
        as = fmaf(xv, Ws[d * DM + lane], as);
        ad = fmaf(xv, Wd[d * DM + lane], ad);
    }
    xs[n * DM + lane] = as + bs[lane];
    xd[n * DM + lane] = ad + bd[lane];
}

// xij[e][m] = RBF(bl[e]) @ Wedge + bedge + xs[g_src[e]] + xd[g_dst[e]]
// 64-edge x 64-dm tile per block; RBF A-tile computed on the fly into LDS.
__global__ __launch_bounds__(256) void k_xij(
    const float* __restrict__ bl,
    const float* __restrict__ We, const float* __restrict__ be,
    const float* __restrict__ xs, const float* __restrict__ xd,
    const int* __restrict__ gs, const int* __restrict__ gd,
    float* __restrict__ xij, int E) {
    __shared__ float A[64][65];
    __shared__ float W[64][65];
    int tid = threadIdx.x;
    int e0 = blockIdx.x * 64;
    int ty = tid >> 4, tx = tid & 15;
    const float step = 8.0f / 255.0f;
    const float gamma = (255.0f / 8.0f) * (255.0f / 8.0f);
    float acc[4][4] = {};
    for (int k0 = 0; k0 < DMODEL; k0 += 64) {
        for (int i = 0; i < 16; ++i) {
            int flat = i * 256 + tid;
            int row = flat >> 6;      // wave-uniform
            int col = flat & 63;      // = lane
            int ee = e0 + row;
            float blv = (ee < E) ? bl[ee] : 0.f;
            float c = (float)(k0 + col) * step;
            float dd = blv - c;
            A[row][col] = __expf(-gamma * dd * dd);
            W[row][col] = We[(k0 + row) * DM + col];
        }
        __syncthreads();
        for (int kk = 0; kk < 64; ++kk) {
            float av[4], wv[4];
            for (int i = 0; i < 4; ++i) av[i] = A[ty * 4 + i][kk];
            for (int j = 0; j < 4; ++j) wv[j] = W[kk][tx * 4 + j];
            for (int i = 0; i < 4; ++i)
                for (int j = 0; j < 4; ++j)
                    acc[i][j] = fmaf(av[i], wv[j], acc[i][j]);
        }
        __syncthreads();
    }
    for (int i = 0; i < 4; ++i) {
        int e = e0 + ty * 4 + i;
        if (e >= E) continue;
        int s = gs[e], d2 = gd[e];
        for (int j = 0; j < 4; ++j) {
            int m = tx * 4 + j;
            xij[e * DM + m] = acc[i][j] + xs[s * DM + m] + xd[d2 * DM + m] + be[m];
        }
    }
}

// wave per edge: online softmax over its triplet segment, lane = channel.
__global__ __launch_bounds__(256) void k_triplet(
    const float* __restrict__ xij, const float* __restrict__ thetas,
    const int* __restrict__ srcs, const int* __restrict__ rowp,
    const int* __restrict__ gd, const float* __restrict__ attn_l,
    float* __restrict__ ft, int E, int nwaves) {
    int lane = threadIdx.x & 63;
    int wid = (blockIdx.x * blockDim.x + threadIdx.x) >> 6;
    float ak = attn_l[lane];
    float kf = (float)lane;
    for (int e = wid; e < E; e += nwaves) {
        int beg = rowp[e], end = rowp[e + 1];
        if (beg == end) continue;
        float xe = xij[e * DM + lane];
        float m = -1e30f, den = 0.f, acc = 0.f;
        for (int p = beg; p < end; ++p) {
            int s = srcs[p];
            float th = thetas[p];
            float xsv = xij[s * DM + lane];
            float v = __cosf(kf * th) + xsv + xe;
            float ev = v / (1.0f + __expf(-v));   // silu
            float c = ev * ak;
            for (int off = 32; off > 0; off >>= 1)
                c += __shfl_xor(c, off, 64);      // logit, all lanes
            float nm = fmaxf(m, c);
            float w = __expf(c - nm);
            float sc = __expf(m - nm);
            den = den * sc + w;
            acc = acc * sc + w * xsv;
            m = nm;
        }
        atomicAdd(&ft[gd[e] * DM + lane], acc / den);
    }
}

// h = silu(ft @ W1 + b1) : 32-node x 256-hcol tile per block
__global__ __launch_bounds__(256) void k_ffn1(
    const float* __restrict__ ft, const float* __restrict__ W1,
    const float* __restrict__ b1, float* __restrict__ h, int N) {
    __shared__ float sft[32][65];
    int tid = threadIdx.x;
    int n0 = blockIdx.x * 32;
    int h0 = blockIdx.y * 256;
    for (int i = 0; i < 8; ++i) {
        int flat = i * 256 + tid;
        int nl = flat >> 6, d = flat & 63;
        int n = n0 + nl;
        sft[nl][d] = (n < N) ? ft[n * DM + d] : 0.f;
    }
    __syncthreads();
    int hc = h0 + tid;
    float acc[32];
    for (int j = 0; j < 32; ++j) acc[j] = 0.f;
    for (int d = 0; d < DM; ++d) {
        float w = W1[d * HDIM + hc];
        for (int j = 0; j < 32; ++j) acc[j] = fmaf(sft[j][d], w, acc[j]);
    }
    float bb = b1[hc];
    int nmax = min(32, N - n0);
    for (int j = 0; j < nmax; ++j) {
        float v = acc[j] + bb;
        h[(size_t)(n0 + j) * HDIM + hc] = v / (1.0f + __expf(-v));  // silu fused
    }
}

// x = h @ W2 + b2 : 32-node x 256-col tile per block (full D width)
__global__ __launch_bounds__(256) void k_ffn2(
    const float* __restrict__ h, const float* __restrict__ W2,
    const float* __restrict__ b2, float* __restrict__ x, int N) {
    __shared__ float sh[32][129];
    int tid = threadIdx.x;
    int n0 = blockIdx.x * 32;
    float acc[32];
    for (int j = 0; j < 32; ++j) acc[j] = 0.f;
    for (int h0 = 0; h0 < HDIM; h0 += 128) {
        for (int i = 0; i < 16; ++i) {
            int flat = i * 256 + tid;
            int nl = flat >> 7, hh = flat & 127;
            int n = n0 + nl;
            sh[nl][hh] = (n < N) ? h[(size_t)n * HDIM + h0 + hh] : 0.f;
        }
        __syncthreads();
        for (int hh = 0; hh < 128; ++hh) {
            float w = W2[(h0 + hh) * DMODEL + tid];
            for (int j = 0; j < 32; ++j) acc[j] = fmaf(sh[j][hh], w, acc[j]);
        }
        __syncthreads();
    }
    float bb = b2[tid];
    int nmax = min(32, N - n0);
    for (int j = 0; j < nmax; ++j)
        x[(n0 + j) * DMODEL + tid] = acc[j] + bb;
}

__global__ void k_out_reduce(const float* __restrict__ x, const float* __restrict__ Wfc,
                             float* __restrict__ acc, int NT) {
    int i = blockIdx.x * blockDim.x + threadIdx.x;
    float v = 0.f;
    if (i < NT) v = x[i] * Wfc[i & (DMODEL - 1)];
    for (int off = 32; off > 0; off >>= 1) v += __shfl_xor(v, off, 64);
    if ((threadIdx.x & 63) == 0) atomicAdd(acc, v);
}

__global__ void k_out_final(const float* __restrict__ acc, const float* __restrict__ bfc,
                            float* __restrict__ out, float invN) {
    out[0] = acc[0] * invN + bfc[0];
}

extern "C" void kernel_launch(void* const* d_in, const int* in_sizes, int n_in,
                              void* d_out, int out_size, void* d_ws, size_t ws_size,
                              hipStream_t stream) {
    const int*   an    = (const int*)d_in[0];
    const int*   gs    = (const int*)d_in[1];
    const int*   gd    = (const int*)d_in[2];
    const int*   ts    = (const int*)d_in[3];
    const int*   td    = (const int*)d_in[4];
    const float* r     = (const float*)d_in[5];
    const float* emb   = (const float*)d_in[6];
    const float* Wsrc  = (const float*)d_in[7];
    const float* bsrc  = (const float*)d_in[8];
    const float* Wdst  = (const float*)d_in[9];
    const float* bdst  = (const float*)d_in[10];
    const float* Wedge = (const float*)d_in[11];
    const float* bedge = (const float*)d_in[12];
    const float* attn  = (const float*)d_in[13];
    const float* W1    = (const float*)d_in[14];
    const float* b1    = (const float*)d_in[15];
    const float* W2    = (const float*)d_in[16];
    const float* b2    = (const float*)d_in[17];
    const float* Wfc   = (const float*)d_in[18];
    const float* bfc   = (const float*)d_in[19];

    const int N = in_sizes[0];
    const int E = in_sizes[1];
    const int T = in_sizes[3];

    char* w = (char*)d_ws;
    size_t off = 0;
    auto alloc = [&](size_t elems) {
        void* p = w + off;
        off += ((elems * 4 + 255) / 256) * 256;
        return p;
    };
    float* x      = (float*)alloc((size_t)N * DMODEL);
    float* rn     = (float*)alloc((size_t)E * 3);
    float* bl     = (float*)alloc((size_t)E);
    int*   cnt    = (int*)  alloc((size_t)E);
    int*   rowp   = (int*)  alloc((size_t)E + 1);
    int*   srcs   = (int*)  alloc((size_t)T);
    float* thetas = (float*)alloc((size_t)T);
    float* xs     = (float*)alloc((size_t)N * DM);
    float* xd     = (float*)alloc((size_t)N * DM);
    float* xij    = (float*)alloc((size_t)E * DM);
    float* ft     = (float*)alloc((size_t)N * DM);
    float* h      = (float*)alloc((size_t)N * HDIM);
    float* accs   = (float*)alloc(16);
    (void)ws_size; (void)n_in; (void)out_size;

    // ---- setup (layer-invariant) ----
    k_embed<<<N, 256, 0, stream>>>(an, emb, x);
    k_edge_geom<<<(E + 255) / 256, 256, 0, stream>>>(r, bl, rn, E);
    hipMemsetAsync(cnt, 0, (size_t)E * 4, stream);
    k_hist<<<(T + 255) / 256, 256, 0, stream>>>(td, cnt, T);
    k_scan<<<1, 1024, 0, stream>>>(cnt, rowp, E, T);
    hipMemsetAsync(cnt, 0, (size_t)E * 4, stream);
    k_scatter<<<(T + 255) / 256, 256, 0, stream>>>(ts, td, rowp, cnt, rn, srcs, thetas, T);

    // ---- layers ----
    for (int l = 0; l < 3; ++l) {
        k_node_proj<<<(N + 3) / 4, 256, 0, stream>>>(
            x, Wsrc + l * DMODEL * DM, bsrc + l * DM,
            Wdst + l * DMODEL * DM, bdst + l * DM, xs, xd, N);
        k_xij<<<(E + 63) / 64, 256, 0, stream>>>(
            bl, Wedge + l * DMODEL * DM, bedge + l * DM, xs, xd, gs, gd, xij, E);
        hipMemsetAsync(ft, 0, (size_t)N * DM * 4, stream);
        k_triplet<<<2500, 256, 0, stream>>>(
            xij, thetas, srcs, rowp, gd, attn + l * DM, ft, E, 2500 * 4);
        k_ffn1<<<dim3((N + 31) / 32, HDIM / 256), 256, 0, stream>>>(
            ft, W1 + l * DM * HDIM, b1 + l * HDIM, h, N);
        k_ffn2<<<(N + 31) / 32, 256, 0, stream>>>(
            h, W2 + l * HDIM * DMODEL, b2 + l * DMODEL, x, N);
    }

    // ---- output head ----
    hipMemsetAsync(accs, 0, 4, stream);
    k_out_reduce<<<(N * DMODEL + 255) / 256, 256, 0, stream>>>(x, Wfc, accs, N * DMODEL);
    k_out_final<<<1, 1, 0, stream>>>(accs, bfc, (float*)d_out, 1.0f / (float)N);
}

// Round 2
// 2923.582 us; speedup vs baseline: 1.1483x; 1.1483x over previous
//
#include <hip/hip_runtime.h>
#include <math.h>

// M3GNet-like GNN forward. N=10000 nodes, E=160000 edges, T=1200000 triplets,
// D=256, DM=64, H=1024, L=3, output = scalar mean energy (fp32).
//
// R1: fix k_out_reduce atomic serialization (40000 same-address atomics ->
// 120, via per-block LDS reduction). Everything else unchanged from R0.

#define DM 64
#define DMODEL 256
#define HDIM 1024

__global__ void k_embed(const int* __restrict__ an, const float* __restrict__ emb,
                        float* __restrict__ x) {
    int n = blockIdx.x;
    int d = threadIdx.x;          // blockDim = 256
    x[n * DMODEL + d] = emb[an[n] * DMODEL + d];
}

__global__ void k_edge_geom(const float* __restrict__ r, float* __restrict__ bl,
                            float* __restrict__ rn, int E) {
    int e = blockIdx.x * blockDim.x + threadIdx.x;
    if (e >= E) return;
    float a = r[e * 3 + 0], b = r[e * 3 + 1], c = r[e * 3 + 2];
    float l = sqrtf(a * a + b * b + c * c);
    bl[e] = l;
    float inv = 1.0f / l;
    // note: reference uses -r/|r| for both operands of the dot; signs cancel.
    rn[e * 3 + 0] = a * inv;
    rn[e * 3 + 1] = b * inv;
    rn[e * 3 + 2] = c * inv;
}

__global__ void k_hist(const int* __restrict__ td, int* __restrict__ cnt, int T) {
    int t = blockIdx.x * blockDim.x + threadIdx.x;
    if (t < T) atomicAdd(&cnt[td[t]], 1);
}

// single-block exclusive scan over cnt[E] -> rowp[E+1]
__global__ void k_scan(const int* __restrict__ cnt, int* __restrict__ rowp,
                       int E, int T) {
    __shared__ int sm[1024];
    int tid = threadIdx.x;
    int chunk = (E + 1023) >> 10;
    int lo = tid * chunk;
    int hi = min(E, lo + chunk);
    int s = 0;
    for (int i = lo; i < hi; ++i) s += cnt[i];
    sm[tid] = s;
    __syncthreads();
    for (int off = 1; off < 1024; off <<= 1) {
        int v = (tid >= off) ? sm[tid - off] : 0;
        __syncthreads();
        sm[tid] += v;
        __syncthreads();
    }
    int run = (tid == 0) ? 0 : sm[tid - 1];
    for (int i = lo; i < hi; ++i) { rowp[i] = run; run += cnt[i]; }
    if (tid == 0) rowp[E] = T;
}

// scatter triplets into segment order; fuse theta computation; permute t_src.
__global__ void k_scatter(const int* __restrict__ ts, const int* __restrict__ td,
                          const int* __restrict__ rowp, int* __restrict__ cursor,
                          const float* __restrict__ rn,
                          int* __restrict__ srcs, float* __restrict__ thetas, int T) {
    int t = blockIdx.x * blockDim.x + threadIdx.x;
    if (t >= T) return;
    int a = ts[t], b = td[t];
    float d = rn[a * 3 + 0] * rn[b * 3 + 0]
            + rn[a * 3 + 1] * rn[b * 3 + 1]
            + rn[a * 3 + 2] * rn[b * 3 + 2];
    d = fminf(1.0f, fmaxf(-1.0f, d));
    float th = acosf(d);
    int pos = rowp[b] + atomicAdd(&cursor[b], 1);
    srcs[pos] = a;
    thetas[pos] = th;
}

// xs = x@Wsrc + bsrc ; xd = x@Wdst + bdst   (wave per node, lane = dm)
__global__ __launch_bounds__(256) void k_node_proj(
    const float* __restrict__ x,
    const float* __restrict__ Ws, const float* __restrict__ bs,
    const float* __restrict__ Wd, const float* __restrict__ bd,
    float* __restrict__ xs, float* __restrict__ xd, int N) {
    int lane = threadIdx.x & 63;
    int n = blockIdx.x * 4 + (threadIdx.x >> 6);
    if (n >= N) return;
    const float* xr = x + (size_t)n * DMODEL;
    float as = 0.f, ad = 0.f;
    for (int d = 0; d < DMODEL; ++d) {
        float xv = xr[d];
        as = fmaf(xv, Ws[d * DM + lane], as);
        ad = fmaf(xv, Wd[d * DM + lane], ad);
    }
    xs[n * DM + lane] = as + bs[lane];
    xd[n * DM + lane] = ad + bd[lane];
}

// xij[e][m] = RBF(bl[e]) @ Wedge + bedge + xs[g_src[e]] + xd[g_dst[e]]
// 64-edge x 64-dm tile per block; RBF A-tile computed on the fly into LDS.
__global__ __launch_bounds__(256) void k_xij(
    const float* __restrict__ bl,
    const float* __restrict__ We, const float* __restrict__ be,
    const float* __restrict__ xs, const float* __restrict__ xd,
    const int* __restrict__ gs, const int* __restrict__ gd,
    float* __restrict__ xij, int E) {
    __shared__ float A[64][65];
    __shared__ float W[64][65];
    int tid = threadIdx.x;
    int e0 = blockIdx.x * 64;
    int ty = tid >> 4, tx = tid & 15;
    const float step = 8.0f / 255.0f;
    const float gamma = (255.0f / 8.0f) * (255.0f / 8.0f);
    float acc[4][4] = {};
    for (int k0 = 0; k0 < DMODEL; k0 += 64) {
        for (int i = 0; i < 16; ++i) {
            int flat = i * 256 + tid;
            int row = flat >> 6;      // wave-uniform
            int col = flat & 63;      // = lane
            int ee = e0 + row;
            float blv = (ee < E) ? bl[ee] : 0.f;
            float c = (float)(k0 + col) * step;
            float dd = blv - c;
            A[row][col] = __expf(-gamma * dd * dd);
            W[row][col] = We[(k0 + row) * DM + col];
        }
        __syncthreads();
        for (int kk = 0; kk < 64; ++kk) {
            float av[4], wv[4];
            for (int i = 0; i < 4; ++i) av[i] = A[ty * 4 + i][kk];
            for (int j = 0; j < 4; ++j) wv[j] = W[kk][tx * 4 + j];
            for (int i = 0; i < 4; ++i)
                for (int j = 0; j < 4; ++j)
                    acc[i][j] = fmaf(av[i], wv[j], acc[i][j]);
        }
        __syncthreads();
    }
    for (int i = 0; i < 4; ++i) {
        int e = e0 + ty * 4 + i;
        if (e >= E) continue;
        int s = gs[e], d2 = gd[e];
        for (int j = 0; j < 4; ++j) {
            int m = tx * 4 + j;
            xij[e * DM + m] = acc[i][j] + xs[s * DM + m] + xd[d2 * DM + m] + be[m];
        }
    }
}

// wave per edge: online softmax over its triplet segment, lane = channel.
__global__ __launch_bounds__(256) void k_triplet(
    const float* __restrict__ xij, const float* __restrict__ thetas,
    const int* __restrict__ srcs, const int* __restrict__ rowp,
    const int* __restrict__ gd, const float* __restrict__ attn_l,
    float* __restrict__ ft, int E, int nwaves) {
    int lane = threadIdx.x & 63;
    int wid = (blockIdx.x * blockDim.x + threadIdx.x) >> 6;
    float ak = attn_l[lane];
    float kf = (float)lane;
    for (int e = wid; e < E; e += nwaves) {
        int beg = rowp[e], end = rowp[e + 1];
        if (beg == end) continue;
        float xe = xij[e * DM + lane];
        float m = -1e30f, den = 0.f, acc = 0.f;
        for (int p = beg; p < end; ++p) {
            int s = srcs[p];
            float th = thetas[p];
            float xsv = xij[s * DM + lane];
            float v = __cosf(kf * th) + xsv + xe;
            float ev = v / (1.0f + __expf(-v));   // silu
            float c = ev * ak;
            for (int off = 32; off > 0; off >>= 1)
                c += __shfl_xor(c, off, 64);      // logit, all lanes
            float nm = fmaxf(m, c);
            float w = __expf(c - nm);
            float sc = __expf(m - nm);
            den = den * sc + w;
            acc = acc * sc + w * xsv;
            m = nm;
        }
        atomicAdd(&ft[gd[e] * DM + lane], acc / den);
    }
}

// h = silu(ft @ W1 + b1) : 32-node x 256-hcol tile per block
__global__ __launch_bounds__(256) void k_ffn1(
    const float* __restrict__ ft, const float* __restrict__ W1,
    const float* __restrict__ b1, float* __restrict__ h, int N) {
    __shared__ float sft[32][65];
    int tid = threadIdx.x;
    int n0 = blockIdx.x * 32;
    int h0 = blockIdx.y * 256;
    for (int i = 0; i < 8; ++i) {
        int flat = i * 256 + tid;
        int nl = flat >> 6, d = flat & 63;
        int n = n0 + nl;
        sft[nl][d] = (n < N) ? ft[n * DM + d] : 0.f;
    }
    __syncthreads();
    int hc = h0 + tid;
    float acc[32];
    for (int j = 0; j < 32; ++j) acc[j] = 0.f;
    for (int d = 0; d < DM; ++d) {
        float w = W1[d * HDIM + hc];
        for (int j = 0; j < 32; ++j) acc[j] = fmaf(sft[j][d], w, acc[j]);
    }
    float bb = b1[hc];
    int nmax = min(32, N - n0);
    for (int j = 0; j < nmax; ++j) {
        float v = acc[j] + bb;
        h[(size_t)(n0 + j) * HDIM + hc] = v / (1.0f + __expf(-v));  // silu fused
    }
}

// x = h @ W2 + b2 : 32-node x 256-col tile per block (full D width)
__global__ __launch_bounds__(256) void k_ffn2(
    const float* __restrict__ h, const float* __restrict__ W2,
    const float* __restrict__ b2, float* __restrict__ x, int N) {
    __shared__ float sh[32][129];
    int tid = threadIdx.x;
    int n0 = blockIdx.x * 32;
    float acc[32];
    for (int j = 0; j < 32; ++j) acc[j] = 0.f;
    for (int h0 = 0; h0 < HDIM; h0 += 128) {
        for (int i = 0; i < 16; ++i) {
            int flat = i * 256 + tid;
            int nl = flat >> 7, hh = flat & 127;
            int n = n0 + nl;
            sh[nl][hh] = (n < N) ? h[(size_t)n * HDIM + h0 + hh] : 0.f;
        }
        __syncthreads();
        for (int hh = 0; hh < 128; ++hh) {
            float w = W2[(h0 + hh) * DMODEL + tid];
            for (int j = 0; j < 32; ++j) acc[j] = fmaf(sh[j][hh], w, acc[j]);
        }
        __syncthreads();
    }
    float bb = b2[tid];
    int nmax = min(32, N - n0);
    for (int j = 0; j < nmax; ++j)
        x[(n0 + j) * DMODEL + tid] = acc[j] + bb;
}

// grid-stride dot(x, tiled Wfc) with per-block LDS reduction -> 1 atomic/block.
__global__ __launch_bounds__(256) void k_out_reduce(
    const float* __restrict__ x, const float* __restrict__ Wfc,
    float* __restrict__ acc, int NT) {
    __shared__ float sm[4];
    int tid = threadIdx.x;
    float v = 0.f;
    for (int i = blockIdx.x * blockDim.x + tid; i < NT; i += gridDim.x * blockDim.x)
        v = fmaf(x[i], Wfc[i & (DMODEL - 1)], v);
    for (int off = 32; off > 0; off >>= 1) v += __shfl_xor(v, off, 64);
    if ((tid & 63) == 0) sm[tid >> 6] = v;
    __syncthreads();
    if (tid == 0) {
        float s = sm[0] + sm[1] + sm[2] + sm[3];
        atomicAdd(acc, s);
    }
}

__global__ void k_out_final(const float* __restrict__ acc, const float* __restrict__ bfc,
                            float* __restrict__ out, float invN) {
    out[0] = acc[0] * invN + bfc[0];
}

extern "C" void kernel_launch(void* const* d_in, const int* in_sizes, int n_in,
                              void* d_out, int out_size, void* d_ws, size_t ws_size,
                              hipStream_t stream) {
    const int*   an    = (const int*)d_in[0];
    const int*   gs    = (const int*)d_in[1];
    const int*   gd    = (const int*)d_in[2];
    const int*   ts    = (const int*)d_in[3];
    const int*   td    = (const int*)d_in[4];
    const float* r     = (const float*)d_in[5];
    const float* emb   = (const float*)d_in[6];
    const float* Wsrc  = (const float*)d_in[7];
    const float* bsrc  = (const float*)d_in[8];
    const float* Wdst  = (const float*)d_in[9];
    const float* bdst  = (const float*)d_in[10];
    const float* Wedge = (const float*)d_in[11];
    const float* bedge = (const float*)d_in[12];
    const float* attn  = (const float*)d_in[13];
    const float* W1    = (const float*)d_in[14];
    const float* b1    = (const float*)d_in[15];
    const float* W2    = (const float*)d_in[16];
    const float* b2    = (const float*)d_in[17];
    const float* Wfc   = (const float*)d_in[18];
    const float* bfc   = (const float*)d_in[19];

    const int N = in_sizes[0];
    const int E = in_sizes[1];
    const int T = in_sizes[3];

    char* w = (char*)d_ws;
    size_t off = 0;
    auto alloc = [&](size_t elems) {
        void* p = w + off;
        off += ((elems * 4 + 255) / 256) * 256;
        return p;
    };
    float* x      = (float*)alloc((size_t)N * DMODEL);
    float* rn     = (float*)alloc((size_t)E * 3);
    float* bl     = (float*)alloc((size_t)E);
    int*   cnt    = (int*)  alloc((size_t)E);
    int*   rowp   = (int*)  alloc((size_t)E + 1);
    int*   srcs   = (int*)  alloc((size_t)T);
    float* thetas = (float*)alloc((size_t)T);
    float* xs     = (float*)alloc((size_t)N * DM);
    float* xd     = (float*)alloc((size_t)N * DM);
    float* xij    = (float*)alloc((size_t)E * DM);
    float* ft     = (float*)alloc((size_t)N * DM);
    float* h      = (float*)alloc((size_t)N * HDIM);
    float* accs   = (float*)alloc(16);
    (void)ws_size; (void)n_in; (void)out_size;

    // ---- setup (layer-invariant) ----
    k_embed<<<N, 256, 0, stream>>>(an, emb, x);
    k_edge_geom<<<(E + 255) / 256, 256, 0, stream>>>(r, bl, rn, E);
    hipMemsetAsync(cnt, 0, (size_t)E * 4, stream);
    k_hist<<<(T + 255) / 256, 256, 0, stream>>>(td, cnt, T);
    k_scan<<<1, 1024, 0, stream>>>(cnt, rowp, E, T);
    hipMemsetAsync(cnt, 0, (size_t)E * 4, stream);
    k_scatter<<<(T + 255) / 256, 256, 0, stream>>>(ts, td, rowp, cnt, rn, srcs, thetas, T);

    // ---- layers ----
    for (int l = 0; l < 3; ++l) {
        k_node_proj<<<(N + 3) / 4, 256, 0, stream>>>(
            x, Wsrc + l * DMODEL * DM, bsrc + l * DM,
            Wdst + l * DMODEL * DM, bdst + l * DM, xs, xd, N);
        k_xij<<<(E + 63) / 64, 256, 0, stream>>>(
            bl, Wedge + l * DMODEL * DM, bedge + l * DM, xs, xd, gs, gd, xij, E);
        hipMemsetAsync(ft, 0, (size_t)N * DM * 4, stream);
        k_triplet<<<2500, 256, 0, stream>>>(
            xij, thetas, srcs, rowp, gd, attn + l * DM, ft, E, 2500 * 4);
        k_ffn1<<<dim3((N + 31) / 32, HDIM / 256), 256, 0, stream>>>(
            ft, W1 + l * DM * HDIM, b1 + l * HDIM, h, N);
        k_ffn2<<<(N + 31) / 32, 256, 0, stream>>>(
            h, W2 + l * HDIM * DMODEL, b2 + l * DMODEL, x, N);
    }

    // ---- output head ----
    hipMemsetAsync(accs, 0, 4, stream);
    k_out_reduce<<<120, 256, 0, stream>>>(x, Wfc, accs, N * DMODEL);
    k_out_final<<<1, 1, 0, stream>>>(accs, bfc, (float*)d_out, 1.0f / (float)N);
}

// Round 3
// 2213.532 us; speedup vs baseline: 1.5167x; 1.3208x over previous
//
#include <hip/hip_runtime.h>
#include <math.h>

// M3GNet-like GNN forward. N=10000 nodes, E=160000 edges, T=1200000 triplets,
// D=256, DM=64, H=1024, L=3, output = scalar mean energy (fp32).
//
// R2: rewrite FFN GEMMs with 64x64 tiles + 4x4 register blocking (k_xij
// pattern). R1's k_ffn2 was latency-bound: 313 blocks (1.2/CU), 1 LDS read
// per FMA, VALUBusy 16%. New: 628/2512 blocks, ds_read_b128, float4 stores.

#define DM 64
#define DMODEL 256
#define HDIM 1024

__global__ void k_embed(const int* __restrict__ an, const float* __restrict__ emb,
                        float* __restrict__ x) {
    int n = blockIdx.x;
    int d = threadIdx.x;          // blockDim = 256
    x[n * DMODEL + d] = emb[an[n] * DMODEL + d];
}

__global__ void k_edge_geom(const float* __restrict__ r, float* __restrict__ bl,
                            float* __restrict__ rn, int E) {
    int e = blockIdx.x * blockDim.x + threadIdx.x;
    if (e >= E) return;
    float a = r[e * 3 + 0], b = r[e * 3 + 1], c = r[e * 3 + 2];
    float l = sqrtf(a * a + b * b + c * c);
    bl[e] = l;
    float inv = 1.0f / l;
    // note: reference uses -r/|r| for both operands of the dot; signs cancel.
    rn[e * 3 + 0] = a * inv;
    rn[e * 3 + 1] = b * inv;
    rn[e * 3 + 2] = c * inv;
}

__global__ void k_hist(const int* __restrict__ td, int* __restrict__ cnt, int T) {
    int t = blockIdx.x * blockDim.x + threadIdx.x;
    if (t < T) atomicAdd(&cnt[td[t]], 1);
}

// single-block exclusive scan over cnt[E] -> rowp[E+1]
__global__ void k_scan(const int* __restrict__ cnt, int* __restrict__ rowp,
                       int E, int T) {
    __shared__ int sm[1024];
    int tid = threadIdx.x;
    int chunk = (E + 1023) >> 10;
    int lo = tid * chunk;
    int hi = min(E, lo + chunk);
    int s = 0;
    for (int i = lo; i < hi; ++i) s += cnt[i];
    sm[tid] = s;
    __syncthreads();
    for (int off = 1; off < 1024; off <<= 1) {
        int v = (tid >= off) ? sm[tid - off] : 0;
        __syncthreads();
        sm[tid] += v;
        __syncthreads();
    }
    int run = (tid == 0) ? 0 : sm[tid - 1];
    for (int i = lo; i < hi; ++i) { rowp[i] = run; run += cnt[i]; }
    if (tid == 0) rowp[E] = T;
}

// scatter triplets into segment order; fuse theta computation; permute t_src.
__global__ void k_scatter(const int* __restrict__ ts, const int* __restrict__ td,
                          const int* __restrict__ rowp, int* __restrict__ cursor,
                          const float* __restrict__ rn,
                          int* __restrict__ srcs, float* __restrict__ thetas, int T) {
    int t = blockIdx.x * blockDim.x + threadIdx.x;
    if (t >= T) return;
    int a = ts[t], b = td[t];
    float d = rn[a * 3 + 0] * rn[b * 3 + 0]
            + rn[a * 3 + 1] * rn[b * 3 + 1]
            + rn[a * 3 + 2] * rn[b * 3 + 2];
    d = fminf(1.0f, fmaxf(-1.0f, d));
    float th = acosf(d);
    int pos = rowp[b] + atomicAdd(&cursor[b], 1);
    srcs[pos] = a;
    thetas[pos] = th;
}

// xs = x@Wsrc + bsrc ; xd = x@Wdst + bdst   (wave per node, lane = dm)
__global__ __launch_bounds__(256) void k_node_proj(
    const float* __restrict__ x,
    const float* __restrict__ Ws, const float* __restrict__ bs,
    const float* __restrict__ Wd, const float* __restrict__ bd,
    float* __restrict__ xs, float* __restrict__ xd, int N) {
    int lane = threadIdx.x & 63;
    int n = blockIdx.x * 4 + (threadIdx.x >> 6);
    if (n >= N) return;
    const float* xr = x + (size_t)n * DMODEL;
    float as = 0.f, ad = 0.f;
    for (int d = 0; d < DMODEL; ++d) {
        float xv = xr[d];
        as = fmaf(xv, Ws[d * DM + lane], as);
        ad = fmaf(xv, Wd[d * DM + lane], ad);
    }
    xs[n * DM + lane] = as + bs[lane];
    xd[n * DM + lane] = ad + bd[lane];
}

// xij[e][m] = RBF(bl[e]) @ Wedge + bedge + xs[g_src[e]] + xd[g_dst[e]]
// 64-edge x 64-dm tile per block; RBF A-tile computed on the fly into LDS.
__global__ __launch_bounds__(256) void k_xij(
    const float* __restrict__ bl,
    const float* __restrict__ We, const float* __restrict__ be,
    const float* __restrict__ xs, const float* __restrict__ xd,
    const int* __restrict__ gs, const int* __restrict__ gd,
    float* __restrict__ xij, int E) {
    __shared__ float A[64][65];
    __shared__ float W[64][65];
    int tid = threadIdx.x;
    int e0 = blockIdx.x * 64;
    int ty = tid >> 4, tx = tid & 15;
    const float step = 8.0f / 255.0f;
    const float gamma = (255.0f / 8.0f) * (255.0f / 8.0f);
    float acc[4][4] = {};
    for (int k0 = 0; k0 < DMODEL; k0 += 64) {
        for (int i = 0; i < 16; ++i) {
            int flat = i * 256 + tid;
            int row = flat >> 6;      // wave-uniform
            int col = flat & 63;      // = lane
            int ee = e0 + row;
            float blv = (ee < E) ? bl[ee] : 0.f;
            float c = (float)(k0 + col) * step;
            float dd = blv - c;
            A[row][col] = __expf(-gamma * dd * dd);
            W[row][col] = We[(k0 + row) * DM + col];
        }
        __syncthreads();
        for (int kk = 0; kk < 64; ++kk) {
            float av[4], wv[4];
            for (int i = 0; i < 4; ++i) av[i] = A[ty * 4 + i][kk];
            for (int j = 0; j < 4; ++j) wv[j] = W[kk][tx * 4 + j];
            for (int i = 0; i < 4; ++i)
                for (int j = 0; j < 4; ++j)
                    acc[i][j] = fmaf(av[i], wv[j], acc[i][j]);
        }
        __syncthreads();
    }
    for (int i = 0; i < 4; ++i) {
        int e = e0 + ty * 4 + i;
        if (e >= E) continue;
        int s = gs[e], d2 = gd[e];
        for (int j = 0; j < 4; ++j) {
            int m = tx * 4 + j;
            xij[e * DM + m] = acc[i][j] + xs[s * DM + m] + xd[d2 * DM + m] + be[m];
        }
    }
}

// wave per edge: online softmax over its triplet segment, lane = channel.
__global__ __launch_bounds__(256) void k_triplet(
    const float* __restrict__ xij, const float* __restrict__ thetas,
    const int* __restrict__ srcs, const int* __restrict__ rowp,
    const int* __restrict__ gd, const float* __restrict__ attn_l,
    float* __restrict__ ft, int E, int nwaves) {
    int lane = threadIdx.x & 63;
    int wid = (blockIdx.x * blockDim.x + threadIdx.x) >> 6;
    float ak = attn_l[lane];
    float kf = (float)lane;
    for (int e = wid; e < E; e += nwaves) {
        int beg = rowp[e], end = rowp[e + 1];
        if (beg == end) continue;
        float xe = xij[e * DM + lane];
        float m = -1e30f, den = 0.f, acc = 0.f;
        for (int p = beg; p < end; ++p) {
            int s = srcs[p];
            float th = thetas[p];
            float xsv = xij[s * DM + lane];
            float v = __cosf(kf * th) + xsv + xe;
            float ev = v / (1.0f + __expf(-v));   // silu
            float c = ev * ak;
            for (int off = 32; off > 0; off >>= 1)
                c += __shfl_xor(c, off, 64);      // logit, all lanes
            float nm = fmaxf(m, c);
            float w = __expf(c - nm);
            float sc = __expf(m - nm);
            den = den * sc + w;
            acc = acc * sc + w * xsv;
            m = nm;
        }
        atomicAdd(&ft[gd[e] * DM + lane], acc / den);
    }
}

// h = silu(ft @ W1 + b1): 64-node x 64-hcol tile, 4x4 register blocking.
// grid (ceil(N/64), HDIM/64) = (157, 16)
__global__ __launch_bounds__(256) void k_ffn1(
    const float* __restrict__ ft, const float* __restrict__ W1,
    const float* __restrict__ b1, float* __restrict__ h, int N) {
    __shared__ float A[32][68];   // A[kk][node], k-major, +4 pad (16B-aligned rows)
    __shared__ float B[32][68];   // B[kk][col]
    int tid = threadIdx.x;
    int n0 = blockIdx.x * 64;
    int c0 = blockIdx.y * 64;
    int ty = tid >> 4, tx = tid & 15;
    float acc[4][4] = {};
    for (int k0 = 0; k0 < DM; k0 += 32) {
        for (int i = 0; i < 8; ++i) {
            int flat = i * 256 + tid;
            int row = flat >> 5, kk = flat & 31;
            int n = n0 + row;
            A[kk][row] = (n < N) ? ft[(size_t)n * DM + k0 + kk] : 0.f;
        }
        for (int i = 0; i < 8; ++i) {
            int flat = i * 256 + tid;
            int kk = flat >> 6, col = flat & 63;
            B[kk][col] = W1[(size_t)(k0 + kk) * HDIM + c0 + col];
        }
        __syncthreads();
        for (int kk = 0; kk < 32; ++kk) {
            float4 av = *(const float4*)&A[kk][ty * 4];
            float4 bv = *(const float4*)&B[kk][tx * 4];
            float a4[4] = {av.x, av.y, av.z, av.w};
            float b4[4] = {bv.x, bv.y, bv.z, bv.w};
            for (int i = 0; i < 4; ++i)
                for (int j = 0; j < 4; ++j)
                    acc[i][j] = fmaf(a4[i], b4[j], acc[i][j]);
        }
        __syncthreads();
    }
    float4 bb = *(const float4*)&b1[c0 + tx * 4];
    float b4[4] = {bb.x, bb.y, bb.z, bb.w};
    for (int i = 0; i < 4; ++i) {
        int n = n0 + ty * 4 + i;
        if (n >= N) continue;
        float4 o;
        float v0 = acc[i][0] + b4[0], v1 = acc[i][1] + b4[1];
        float v2 = acc[i][2] + b4[2], v3 = acc[i][3] + b4[3];
        o.x = v0 / (1.0f + __expf(-v0));
        o.y = v1 / (1.0f + __expf(-v1));
        o.z = v2 / (1.0f + __expf(-v2));
        o.w = v3 / (1.0f + __expf(-v3));
        *(float4*)&h[(size_t)n * HDIM + c0 + tx * 4] = o;
    }
}

// x = h @ W2 + b2: 64-node x 64-col tile, 4x4 register blocking.
// grid (ceil(N/64), DMODEL/64) = (157, 4)
__global__ __launch_bounds__(256) void k_ffn2(
    const float* __restrict__ h, const float* __restrict__ W2,
    const float* __restrict__ b2, float* __restrict__ x, int N) {
    __shared__ float A[32][68];
    __shared__ float B[32][68];
    int tid = threadIdx.x;
    int n0 = blockIdx.x * 64;
    int c0 = blockIdx.y * 64;
    int ty = tid >> 4, tx = tid & 15;
    float acc[4][4] = {};
    for (int k0 = 0; k0 < HDIM; k0 += 32) {
        for (int i = 0; i < 8; ++i) {
            int flat = i * 256 + tid;
            int row = flat >> 5, kk = flat & 31;
            int n = n0 + row;
            A[kk][row] = (n < N) ? h[(size_t)n * HDIM + k0 + kk] : 0.f;
        }
        for (int i = 0; i < 8; ++i) {
            int flat = i * 256 + tid;
            int kk = flat >> 6, col = flat & 63;
            B[kk][col] = W2[(size_t)(k0 + kk) * DMODEL + c0 + col];
        }
        __syncthreads();
        for (int kk = 0; kk < 32; ++kk) {
            float4 av = *(const float4*)&A[kk][ty * 4];
            float4 bv = *(const float4*)&B[kk][tx * 4];
            float a4[4] = {av.x, av.y, av.z, av.w};
            float b4[4] = {bv.x, bv.y, bv.z, bv.w};
            for (int i = 0; i < 4; ++i)
                for (int j = 0; j < 4; ++j)
                    acc[i][j] = fmaf(a4[i], b4[j], acc[i][j]);
        }
        __syncthreads();
    }
    float4 bb = *(const float4*)&b2[c0 + tx * 4];
    float b4[4] = {bb.x, bb.y, bb.z, bb.w};
    for (int i = 0; i < 4; ++i) {
        int n = n0 + ty * 4 + i;
        if (n >= N) continue;
        float4 o;
        o.x = acc[i][0] + b4[0];
        o.y = acc[i][1] + b4[1];
        o.z = acc[i][2] + b4[2];
        o.w = acc[i][3] + b4[3];
        *(float4*)&x[(size_t)n * DMODEL + c0 + tx * 4] = o;
    }
}

// grid-stride dot(x, tiled Wfc) with per-block LDS reduction -> 1 atomic/block.
__global__ __launch_bounds__(256) void k_out_reduce(
    const float* __restrict__ x, const float* __restrict__ Wfc,
    float* __restrict__ acc, int NT) {
    __shared__ float sm[4];
    int tid = threadIdx.x;
    float v = 0.f;
    for (int i = blockIdx.x * blockDim.x + tid; i < NT; i += gridDim.x * blockDim.x)
        v = fmaf(x[i], Wfc[i & (DMODEL - 1)], v);
    for (int off = 32; off > 0; off >>= 1) v += __shfl_xor(v, off, 64);
    if ((tid & 63) == 0) sm[tid >> 6] = v;
    __syncthreads();
    if (tid == 0) {
        float s = sm[0] + sm[1] + sm[2] + sm[3];
        atomicAdd(acc, s);
    }
}

__global__ void k_out_final(const float* __restrict__ acc, const float* __restrict__ bfc,
                            float* __restrict__ out, float invN) {
    out[0] = acc[0] * invN + bfc[0];
}

extern "C" void kernel_launch(void* const* d_in, const int* in_sizes, int n_in,
                              void* d_out, int out_size, void* d_ws, size_t ws_size,
                              hipStream_t stream) {
    const int*   an    = (const int*)d_in[0];
    const int*   gs    = (const int*)d_in[1];
    const int*   gd    = (const int*)d_in[2];
    const int*   ts    = (const int*)d_in[3];
    const int*   td    = (const int*)d_in[4];
    const float* r     = (const float*)d_in[5];
    const float* emb   = (const float*)d_in[6];
    const float* Wsrc  = (const float*)d_in[7];
    const float* bsrc  = (const float*)d_in[8];
    const float* Wdst  = (const float*)d_in[9];
    const float* bdst  = (const float*)d_in[10];
    const float* Wedge = (const float*)d_in[11];
    const float* bedge = (const float*)d_in[12];
    const float* attn  = (const float*)d_in[13];
    const float* W1    = (const float*)d_in[14];
    const float* b1    = (const float*)d_in[15];
    const float* W2    = (const float*)d_in[16];
    const float* b2    = (const float*)d_in[17];
    const float* Wfc   = (const float*)d_in[18];
    const float* bfc   = (const float*)d_in[19];

    const int N = in_sizes[0];
    const int E = in_sizes[1];
    const int T = in_sizes[3];

    char* w = (char*)d_ws;
    size_t off = 0;
    auto alloc = [&](size_t elems) {
        void* p = w + off;
        off += ((elems * 4 + 255) / 256) * 256;
        return p;
    };
    float* x      = (float*)alloc((size_t)N * DMODEL);
    float* rn     = (float*)alloc((size_t)E * 3);
    float* bl     = (float*)alloc((size_t)E);
    int*   cnt    = (int*)  alloc((size_t)E);
    int*   rowp   = (int*)  alloc((size_t)E + 1);
    int*   srcs   = (int*)  alloc((size_t)T);
    float* thetas = (float*)alloc((size_t)T);
    float* xs     = (float*)alloc((size_t)N * DM);
    float* xd     = (float*)alloc((size_t)N * DM);
    float* xij    = (float*)alloc((size_t)E * DM);
    float* ft     = (float*)alloc((size_t)N * DM);
    float* h      = (float*)alloc((size_t)N * HDIM);
    float* accs   = (float*)alloc(16);
    (void)ws_size; (void)n_in; (void)out_size;

    // ---- setup (layer-invariant) ----
    k_embed<<<N, 256, 0, stream>>>(an, emb, x);
    k_edge_geom<<<(E + 255) / 256, 256, 0, stream>>>(r, bl, rn, E);
    hipMemsetAsync(cnt, 0, (size_t)E * 4, stream);
    k_hist<<<(T + 255) / 256, 256, 0, stream>>>(td, cnt, T);
    k_scan<<<1, 1024, 0, stream>>>(cnt, rowp, E, T);
    hipMemsetAsync(cnt, 0, (size_t)E * 4, stream);
    k_scatter<<<(T + 255) / 256, 256, 0, stream>>>(ts, td, rowp, cnt, rn, srcs, thetas, T);

    // ---- layers ----
    for (int l = 0; l < 3; ++l) {
        k_node_proj<<<(N + 3) / 4, 256, 0, stream>>>(
            x, Wsrc + l * DMODEL * DM, bsrc + l * DM,
            Wdst + l * DMODEL * DM, bdst + l * DM, xs, xd, N);
        k_xij<<<(E + 63) / 64, 256, 0, stream>>>(
            bl, Wedge + l * DMODEL * DM, bedge + l * DM, xs, xd, gs, gd, xij, E);
        hipMemsetAsync(ft, 0, (size_t)N * DM * 4, stream);
        k_triplet<<<2500, 256, 0, stream>>>(
            xij, thetas, srcs, rowp, gd, attn + l * DM, ft, E, 2500 * 4);
        k_ffn1<<<dim3((N + 63) / 64, HDIM / 64), 256, 0, stream>>>(
            ft, W1 + l * DM * HDIM, b1 + l * HDIM, h, N);
        k_ffn2<<<dim3((N + 63) / 64, DMODEL / 64), 256, 0, stream>>>(
            h, W2 + l * HDIM * DMODEL, b2 + l * DMODEL, x, N);
    }

    // ---- output head ----
    hipMemsetAsync(accs, 0, 4, stream);
    k_out_reduce<<<120, 256, 0, stream>>>(x, Wfc, accs, N * DMODEL);
    k_out_final<<<1, 1, 0, stream>>>(accs, bfc, (float*)d_out, 1.0f / (float)N);
}

// Round 4
// 1956.828 us; speedup vs baseline: 1.7156x; 1.1312x over previous
//
#include <hip/hip_runtime.h>
#include <math.h>

// M3GNet-like GNN forward. N=10000 nodes, E=160000 edges, T=1200000 triplets,
// D=256, DM=64, H=1024, L=3, output = scalar mean energy (fp32).
//
// R3: replace single-block k_scan (258 us, 1 CU busy) with 3-phase parallel
// scan (part-sums -> mid scan -> per-block scan+offset). Rest unchanged.

#define DM 64
#define DMODEL 256
#define HDIM 1024

__global__ void k_embed(const int* __restrict__ an, const float* __restrict__ emb,
                        float* __restrict__ x) {
    int n = blockIdx.x;
    int d = threadIdx.x;          // blockDim = 256
    x[n * DMODEL + d] = emb[an[n] * DMODEL + d];
}

__global__ void k_edge_geom(const float* __restrict__ r, float* __restrict__ bl,
                            float* __restrict__ rn, int E) {
    int e = blockIdx.x * blockDim.x + threadIdx.x;
    if (e >= E) return;
    float a = r[e * 3 + 0], b = r[e * 3 + 1], c = r[e * 3 + 2];
    float l = sqrtf(a * a + b * b + c * c);
    bl[e] = l;
    float inv = 1.0f / l;
    // note: reference uses -r/|r| for both operands of the dot; signs cancel.
    rn[e * 3 + 0] = a * inv;
    rn[e * 3 + 1] = b * inv;
    rn[e * 3 + 2] = c * inv;
}

__global__ void k_hist(const int* __restrict__ td, int* __restrict__ cnt, int T) {
    int t = blockIdx.x * blockDim.x + threadIdx.x;
    if (t < T) atomicAdd(&cnt[td[t]], 1);
}

// ---- 3-phase exclusive scan of cnt[E] -> rowp[E+1] ----
__global__ __launch_bounds__(256) void k_scan_part(
    const int* __restrict__ cnt, int* __restrict__ bsum, int E) {
    __shared__ int sm[4];
    int tid = threadIdx.x;
    int i = blockIdx.x * 256 + tid;
    int v = (i < E) ? cnt[i] : 0;
    for (int off = 32; off > 0; off >>= 1) v += __shfl_xor(v, off, 64);
    if ((tid & 63) == 0) sm[tid >> 6] = v;
    __syncthreads();
    if (tid == 0) bsum[blockIdx.x] = sm[0] + sm[1] + sm[2] + sm[3];
}

// single block: in-place exclusive scan of bsum[nb] (nb <= 1024)
__global__ __launch_bounds__(1024) void k_scan_mid(int* __restrict__ bsum, int nb) {
    __shared__ int sm[1024];
    int tid = threadIdx.x;
    int v = (tid < nb) ? bsum[tid] : 0;
    sm[tid] = v;
    __syncthreads();
    for (int off = 1; off < 1024; off <<= 1) {
        int u = (tid >= off) ? sm[tid - off] : 0;
        __syncthreads();
        sm[tid] += u;
        __syncthreads();
    }
    if (tid < nb) bsum[tid] = sm[tid] - v;   // inclusive -> exclusive
}

__global__ __launch_bounds__(256) void k_scan_final(
    const int* __restrict__ cnt, const int* __restrict__ bsum,
    int* __restrict__ rowp, int E, int T) {
    __shared__ int sm[256];
    int tid = threadIdx.x;
    int i = blockIdx.x * 256 + tid;
    int v = (i < E) ? cnt[i] : 0;
    sm[tid] = v;
    __syncthreads();
    for (int off = 1; off < 256; off <<= 1) {
        int u = (tid >= off) ? sm[tid - off] : 0;
        __syncthreads();
        sm[tid] += u;
        __syncthreads();
    }
    if (i < E) rowp[i] = bsum[blockIdx.x] + sm[tid] - v;
    if (i == 0) rowp[E] = T;
}

// scatter triplets into segment order; fuse theta computation; permute t_src.
__global__ void k_scatter(const int* __restrict__ ts, const int* __restrict__ td,
                          const int* __restrict__ rowp, int* __restrict__ cursor,
                          const float* __restrict__ rn,
                          int* __restrict__ srcs, float* __restrict__ thetas, int T) {
    int t = blockIdx.x * blockDim.x + threadIdx.x;
    if (t >= T) return;
    int a = ts[t], b = td[t];
    float d = rn[a * 3 + 0] * rn[b * 3 + 0]
            + rn[a * 3 + 1] * rn[b * 3 + 1]
            + rn[a * 3 + 2] * rn[b * 3 + 2];
    d = fminf(1.0f, fmaxf(-1.0f, d));
    float th = acosf(d);
    int pos = rowp[b] + atomicAdd(&cursor[b], 1);
    srcs[pos] = a;
    thetas[pos] = th;
}

// xs = x@Wsrc + bsrc ; xd = x@Wdst + bdst   (wave per node, lane = dm)
__global__ __launch_bounds__(256) void k_node_proj(
    const float* __restrict__ x,
    const float* __restrict__ Ws, const float* __restrict__ bs,
    const float* __restrict__ Wd, const float* __restrict__ bd,
    float* __restrict__ xs, float* __restrict__ xd, int N) {
    int lane = threadIdx.x & 63;
    int n = blockIdx.x * 4 + (threadIdx.x >> 6);
    if (n >= N) return;
    const float* xr = x + (size_t)n * DMODEL;
    float as = 0.f, ad = 0.f;
    for (int d = 0; d < DMODEL; ++d) {
        float xv = xr[d];
        as = fmaf(xv, Ws[d * DM + lane], as);
        ad = fmaf(xv, Wd[d * DM + lane], ad);
    }
    xs[n * DM + lane] = as + bs[lane];
    xd[n * DM + lane] = ad + bd[lane];
}

// xij[e][m] = RBF(bl[e]) @ Wedge + bedge + xs[g_src[e]] + xd[g_dst[e]]
// 64-edge x 64-dm tile per block; RBF A-tile computed on the fly into LDS.
__global__ __launch_bounds__(256) void k_xij(
    const float* __restrict__ bl,
    const float* __restrict__ We, const float* __restrict__ be,
    const float* __restrict__ xs, const float* __restrict__ xd,
    const int* __restrict__ gs, const int* __restrict__ gd,
    float* __restrict__ xij, int E) {
    __shared__ float A[64][65];
    __shared__ float W[64][65];
    int tid = threadIdx.x;
    int e0 = blockIdx.x * 64;
    int ty = tid >> 4, tx = tid & 15;
    const float step = 8.0f / 255.0f;
    const float gamma = (255.0f / 8.0f) * (255.0f / 8.0f);
    float acc[4][4] = {};
    for (int k0 = 0; k0 < DMODEL; k0 += 64) {
        for (int i = 0; i < 16; ++i) {
            int flat = i * 256 + tid;
            int row = flat >> 6;      // wave-uniform
            int col = flat & 63;      // = lane
            int ee = e0 + row;
            float blv = (ee < E) ? bl[ee] : 0.f;
            float c = (float)(k0 + col) * step;
            float dd = blv - c;
            A[row][col] = __expf(-gamma * dd * dd);
            W[row][col] = We[(k0 + row) * DM + col];
        }
        __syncthreads();
        for (int kk = 0; kk < 64; ++kk) {
            float av[4], wv[4];
            for (int i = 0; i < 4; ++i) av[i] = A[ty * 4 + i][kk];
            for (int j = 0; j < 4; ++j) wv[j] = W[kk][tx * 4 + j];
            for (int i = 0; i < 4; ++i)
                for (int j = 0; j < 4; ++j)
                    acc[i][j] = fmaf(av[i], wv[j], acc[i][j]);
        }
        __syncthreads();
    }
    for (int i = 0; i < 4; ++i) {
        int e = e0 + ty * 4 + i;
        if (e >= E) continue;
        int s = gs[e], d2 = gd[e];
        for (int j = 0; j < 4; ++j) {
            int m = tx * 4 + j;
            xij[e * DM + m] = acc[i][j] + xs[s * DM + m] + xd[d2 * DM + m] + be[m];
        }
    }
}

// wave per edge: online softmax over its triplet segment, lane = channel.
__global__ __launch_bounds__(256) void k_triplet(
    const float* __restrict__ xij, const float* __restrict__ thetas,
    const int* __restrict__ srcs, const int* __restrict__ rowp,
    const int* __restrict__ gd, const float* __restrict__ attn_l,
    float* __restrict__ ft, int E, int nwaves) {
    int lane = threadIdx.x & 63;
    int wid = (blockIdx.x * blockDim.x + threadIdx.x) >> 6;
    float ak = attn_l[lane];
    float kf = (float)lane;
    for (int e = wid; e < E; e += nwaves) {
        int beg = rowp[e], end = rowp[e + 1];
        if (beg == end) continue;
        float xe = xij[e * DM + lane];
        float m = -1e30f, den = 0.f, acc = 0.f;
        for (int p = beg; p < end; ++p) {
            int s = srcs[p];
            float th = thetas[p];
            float xsv = xij[s * DM + lane];
            float v = __cosf(kf * th) + xsv + xe;
            float ev = v / (1.0f + __expf(-v));   // silu
            float c = ev * ak;
            for (int off = 32; off > 0; off >>= 1)
                c += __shfl_xor(c, off, 64);      // logit, all lanes
            float nm = fmaxf(m, c);
            float w = __expf(c - nm);
            float sc = __expf(m - nm);
            den = den * sc + w;
            acc = acc * sc + w * xsv;
            m = nm;
        }
        atomicAdd(&ft[gd[e] * DM + lane], acc / den);
    }
}

// h = silu(ft @ W1 + b1): 64-node x 64-hcol tile, 4x4 register blocking.
// grid (ceil(N/64), HDIM/64) = (157, 16)
__global__ __launch_bounds__(256) void k_ffn1(
    const float* __restrict__ ft, const float* __restrict__ W1,
    const float* __restrict__ b1, float* __restrict__ h, int N) {
    __shared__ float A[32][68];   // A[kk][node], k-major, +4 pad (16B-aligned rows)
    __shared__ float B[32][68];   // B[kk][col]
    int tid = threadIdx.x;
    int n0 = blockIdx.x * 64;
    int c0 = blockIdx.y * 64;
    int ty = tid >> 4, tx = tid & 15;
    float acc[4][4] = {};
    for (int k0 = 0; k0 < DM; k0 += 32) {
        for (int i = 0; i < 8; ++i) {
            int flat = i * 256 + tid;
            int row = flat >> 5, kk = flat & 31;
            int n = n0 + row;
            A[kk][row] = (n < N) ? ft[(size_t)n * DM + k0 + kk] : 0.f;
        }
        for (int i = 0; i < 8; ++i) {
            int flat = i * 256 + tid;
            int kk = flat >> 6, col = flat & 63;
            B[kk][col] = W1[(size_t)(k0 + kk) * HDIM + c0 + col];
        }
        __syncthreads();
        for (int kk = 0; kk < 32; ++kk) {
            float4 av = *(const float4*)&A[kk][ty * 4];
            float4 bv = *(const float4*)&B[kk][tx * 4];
            float a4[4] = {av.x, av.y, av.z, av.w};
            float b4[4] = {bv.x, bv.y, bv.z, bv.w};
            for (int i = 0; i < 4; ++i)
                for (int j = 0; j < 4; ++j)
                    acc[i][j] = fmaf(a4[i], b4[j], acc[i][j]);
        }
        __syncthreads();
    }
    float4 bb = *(const float4*)&b1[c0 + tx * 4];
    float b4[4] = {bb.x, bb.y, bb.z, bb.w};
    for (int i = 0; i < 4; ++i) {
        int n = n0 + ty * 4 + i;
        if (n >= N) continue;
        float4 o;
        float v0 = acc[i][0] + b4[0], v1 = acc[i][1] + b4[1];
        float v2 = acc[i][2] + b4[2], v3 = acc[i][3] + b4[3];
        o.x = v0 / (1.0f + __expf(-v0));
        o.y = v1 / (1.0f + __expf(-v1));
        o.z = v2 / (1.0f + __expf(-v2));
        o.w = v3 / (1.0f + __expf(-v3));
        *(float4*)&h[(size_t)n * HDIM + c0 + tx * 4] = o;
    }
}

// x = h @ W2 + b2: 64-node x 64-col tile, 4x4 register blocking.
// grid (ceil(N/64), DMODEL/64) = (157, 4)
__global__ __launch_bounds__(256) void k_ffn2(
    const float* __restrict__ h, const float* __restrict__ W2,
    const float* __restrict__ b2, float* __restrict__ x, int N) {
    __shared__ float A[32][68];
    __shared__ float B[32][68];
    int tid = threadIdx.x;
    int n0 = blockIdx.x * 64;
    int c0 = blockIdx.y * 64;
    int ty = tid >> 4, tx = tid & 15;
    float acc[4][4] = {};
    for (int k0 = 0; k0 < HDIM; k0 += 32) {
        for (int i = 0; i < 8; ++i) {
            int flat = i * 256 + tid;
            int row = flat >> 5, kk = flat & 31;
            int n = n0 + row;
            A[kk][row] = (n < N) ? h[(size_t)n * HDIM + k0 + kk] : 0.f;
        }
        for (int i = 0; i < 8; ++i) {
            int flat = i * 256 + tid;
            int kk = flat >> 6, col = flat & 63;
            B[kk][col] = W2[(size_t)(k0 + kk) * DMODEL + c0 + col];
        }
        __syncthreads();
        for (int kk = 0; kk < 32; ++kk) {
            float4 av = *(const float4*)&A[kk][ty * 4];
            float4 bv = *(const float4*)&B[kk][tx * 4];
            float a4[4] = {av.x, av.y, av.z, av.w};
            float b4[4] = {bv.x, bv.y, bv.z, bv.w};
            for (int i = 0; i < 4; ++i)
                for (int j = 0; j < 4; ++j)
                    acc[i][j] = fmaf(a4[i], b4[j], acc[i][j]);
        }
        __syncthreads();
    }
    float4 bb = *(const float4*)&b2[c0 + tx * 4];
    float b4[4] = {bb.x, bb.y, bb.z, bb.w};
    for (int i = 0; i < 4; ++i) {
        int n = n0 + ty * 4 + i;
        if (n >= N) continue;
        float4 o;
        o.x = acc[i][0] + b4[0];
        o.y = acc[i][1] + b4[1];
        o.z = acc[i][2] + b4[2];
        o.w = acc[i][3] + b4[3];
        *(float4*)&x[(size_t)n * DMODEL + c0 + tx * 4] = o;
    }
}

// grid-stride dot(x, tiled Wfc) with per-block LDS reduction -> 1 atomic/block.
__global__ __launch_bounds__(256) void k_out_reduce(
    const float* __restrict__ x, const float* __restrict__ Wfc,
    float* __restrict__ acc, int NT) {
    __shared__ float sm[4];
    int tid = threadIdx.x;
    float v = 0.f;
    for (int i = blockIdx.x * blockDim.x + tid; i < NT; i += gridDim.x * blockDim.x)
        v = fmaf(x[i], Wfc[i & (DMODEL - 1)], v);
    for (int off = 32; off > 0; off >>= 1) v += __shfl_xor(v, off, 64);
    if ((tid & 63) == 0) sm[tid >> 6] = v;
    __syncthreads();
    if (tid == 0) {
        float s = sm[0] + sm[1] + sm[2] + sm[3];
        atomicAdd(acc, s);
    }
}

__global__ void k_out_final(const float* __restrict__ acc, const float* __restrict__ bfc,
                            float* __restrict__ out, float invN) {
    out[0] = acc[0] * invN + bfc[0];
}

extern "C" void kernel_launch(void* const* d_in, const int* in_sizes, int n_in,
                              void* d_out, int out_size, void* d_ws, size_t ws_size,
                              hipStream_t stream) {
    const int*   an    = (const int*)d_in[0];
    const int*   gs    = (const int*)d_in[1];
    const int*   gd    = (const int*)d_in[2];
    const int*   ts    = (const int*)d_in[3];
    const int*   td    = (const int*)d_in[4];
    const float* r     = (const float*)d_in[5];
    const float* emb   = (const float*)d_in[6];
    const float* Wsrc  = (const float*)d_in[7];
    const float* bsrc  = (const float*)d_in[8];
    const float* Wdst  = (const float*)d_in[9];
    const float* bdst  = (const float*)d_in[10];
    const float* Wedge = (const float*)d_in[11];
    const float* bedge = (const float*)d_in[12];
    const float* attn  = (const float*)d_in[13];
    const float* W1    = (const float*)d_in[14];
    const float* b1    = (const float*)d_in[15];
    const float* W2    = (const float*)d_in[16];
    const float* b2    = (const float*)d_in[17];
    const float* Wfc   = (const float*)d_in[18];
    const float* bfc   = (const float*)d_in[19];

    const int N = in_sizes[0];
    const int E = in_sizes[1];
    const int T = in_sizes[3];

    char* w = (char*)d_ws;
    size_t off = 0;
    auto alloc = [&](size_t elems) {
        void* p = w + off;
        off += ((elems * 4 + 255) / 256) * 256;
        return p;
    };
    float* x      = (float*)alloc((size_t)N * DMODEL);
    float* rn     = (float*)alloc((size_t)E * 3);
    float* bl     = (float*)alloc((size_t)E);
    int*   cnt    = (int*)  alloc((size_t)E);
    int*   rowp   = (int*)  alloc((size_t)E + 1);
    int*   bsum   = (int*)  alloc(1024);
    int*   srcs   = (int*)  alloc((size_t)T);
    float* thetas = (float*)alloc((size_t)T);
    float* xs     = (float*)alloc((size_t)N * DM);
    float* xd     = (float*)alloc((size_t)N * DM);
    float* xij    = (float*)alloc((size_t)E * DM);
    float* ft     = (float*)alloc((size_t)N * DM);
    float* h      = (float*)alloc((size_t)N * HDIM);
    float* accs   = (float*)alloc(16);
    (void)ws_size; (void)n_in; (void)out_size;

    const int nbScan = (E + 255) / 256;   // 625 <= 1024

    // ---- setup (layer-invariant) ----
    k_embed<<<N, 256, 0, stream>>>(an, emb, x);
    k_edge_geom<<<(E + 255) / 256, 256, 0, stream>>>(r, bl, rn, E);
    hipMemsetAsync(cnt, 0, (size_t)E * 4, stream);
    k_hist<<<(T + 255) / 256, 256, 0, stream>>>(td, cnt, T);
    k_scan_part<<<nbScan, 256, 0, stream>>>(cnt, bsum, E);
    k_scan_mid<<<1, 1024, 0, stream>>>(bsum, nbScan);
    k_scan_final<<<nbScan, 256, 0, stream>>>(cnt, bsum, rowp, E, T);
    hipMemsetAsync(cnt, 0, (size_t)E * 4, stream);
    k_scatter<<<(T + 255) / 256, 256, 0, stream>>>(ts, td, rowp, cnt, rn, srcs, thetas, T);

    // ---- layers ----
    for (int l = 0; l < 3; ++l) {
        k_node_proj<<<(N + 3) / 4, 256, 0, stream>>>(
            x, Wsrc + l * DMODEL * DM, bsrc + l * DM,
            Wdst + l * DMODEL * DM, bdst + l * DM, xs, xd, N);
        k_xij<<<(E + 63) / 64, 256, 0, stream>>>(
            bl, Wedge + l * DMODEL * DM, bedge + l * DM, xs, xd, gs, gd, xij, E);
        hipMemsetAsync(ft, 0, (size_t)N * DM * 4, stream);
        k_triplet<<<2500, 256, 0, stream>>>(
            xij, thetas, srcs, rowp, gd, attn + l * DM, ft, E, 2500 * 4);
        k_ffn1<<<dim3((N + 63) / 64, HDIM / 64), 256, 0, stream>>>(
            ft, W1 + l * DM * HDIM, b1 + l * HDIM, h, N);
        k_ffn2<<<dim3((N + 63) / 64, DMODEL / 64), 256, 0, stream>>>(
            h, W2 + l * HDIM * DMODEL, b2 + l * DMODEL, x, N);
    }

    // ---- output head ----
    hipMemsetAsync(accs, 0, 4, stream);
    k_out_reduce<<<120, 256, 0, stream>>>(x, Wfc, accs, N * DMODEL);
    k_out_final<<<1, 1, 0, stream>>>(accs, bfc, (float*)d_out, 1.0f / (float)N);
}